// Round 12
// baseline (246.217 us; speedup 1.0000x reference)
//
#include <hip/hip_runtime.h>
#include <hip/hip_bf16.h>

// Round-2 finding: ALL inputs and the output are FP32.
// Round-11 post-mortem: attn_mfma had 7.2M LDS bank conflicts (scattered
// b16 P-stores + Gw gathers) + heavy per-lane index VALU.  Round 12:
// TRANSPOSED attention MFMAs (S^T = K.Q^T) so q = col is lane-fixed:
//   - per-lane Gw values chunk-independent -> 8 regs, preloaded once
//   - Gh = 1 broadcast ds_read_u16 / chunk
//   - P^T write = 2x ds_write_b64, PV B-frag = 1x ds_read_b128 (no scatter)
//   - row-sum l via all-ones A-frag -> l[q=col] in every lane, no shuffle
// LDS ops/chunk: 18 -> 4.

typedef __hip_bfloat16 bf16;
using short8 = __attribute__((ext_vector_type(8))) short;
using short4v = __attribute__((ext_vector_type(4))) short;
using f32x4 = __attribute__((ext_vector_type(4))) float;

__device__ __forceinline__ short f2bs(float f) {
  union { bf16 b; short s; } u; u.b = __float2bfloat16(f); return u.s;
}
__device__ __forceinline__ float bs2f(short s) {
  union { unsigned u; float f; } x; x.u = ((unsigned)(unsigned short)s) << 16;
  return x.f;
}

// ---------------------------------------------------------------------------
// Prepass A: xt[b][34][34][256] bf16 = x NCHW -> spatial-major channel-contig
// with zero halo ring.  grid (8, 34), block 256.
// ---------------------------------------------------------------------------
__global__ __launch_bounds__(256) void xpose(
    const float* __restrict__ X, short* __restrict__ xt) {
  const int b = blockIdx.x, r = blockIdx.y;   // r in 0..33 (halo coords)
  const int tid = threadIdx.x;
  const bool rin = (r >= 1) && (r <= 32);
  for (int idx = tid; idx < 34 * 256; idx += 256) {
    int cc = idx >> 8, c = idx & 255;
    float v = 0.f;
    if (rin && cc >= 1 && cc <= 32)
      v = X[((size_t)b * 256 + c) * 1024 + (r - 1) * 32 + (cc - 1)];
    xt[(((size_t)b * 34 + r) * 34 + cc) * 256 + c] = f2bs(v);
  }
}

// ---------------------------------------------------------------------------
// Prepass B: Wb[tap][o][c] bf16 from w_out[o][c][3][3].  grid 2304, block 256.
// ---------------------------------------------------------------------------
__global__ __launch_bounds__(256) void wpack(
    const float* __restrict__ Wc, short* __restrict__ Wb) {
  int idx = blockIdx.x * 256 + threadIdx.x;   // tap*65536 + o*256 + c
  int tap = idx >> 16;
  int rest = idx & 65535;
  int o = rest >> 8, c = rest & 255;
  Wb[idx] = f2bs(Wc[((size_t)o * 256 + c) * 9 + tap]);
}

// ---------------------------------------------------------------------------
// Kernel 1: QKV 1x1 conv as GEMM.  Epilogue emits MFMA-ready bf16:
//   qsb[bnh][q][d] (scaled) | ksb[bnh][key][d] | vtb[bnh][d][key]
// grid (16, 12, 8), block 256.
// ---------------------------------------------------------------------------
__global__ __launch_bounds__(256) void qkv_gemm(
    const float* __restrict__ W, const float* __restrict__ X,
    const float* __restrict__ bias,
    short* __restrict__ qsb, short* __restrict__ ksb, short* __restrict__ vtb) {
  const int b  = blockIdx.z;
  const int p0 = blockIdx.x * 64;
  const int o0 = blockIdx.y * 64;
  const int tid = threadIdx.x;
  const int tx = tid & 15, ty = tid >> 4;
  __shared__ float As[16][64];   // [k][o]
  __shared__ float Bs[16][64];   // [k][p]
  float acc[4][4] = {};
  const float* Xb = X + (size_t)b * 256 * 1024;
  for (int c0 = 0; c0 < 256; c0 += 16) {
    {
      int r = tid >> 2, c4 = (tid & 3) * 4;
      float4 w4 = *(const float4*)(W + (size_t)(o0 + r) * 256 + c0 + c4);
      As[c4 + 0][r] = w4.x; As[c4 + 1][r] = w4.y;
      As[c4 + 2][r] = w4.z; As[c4 + 3][r] = w4.w;
    }
    {
      int r = tid >> 4, cp = (tid & 15) * 4;
      float4 x4 = *(const float4*)(Xb + (size_t)(c0 + r) * 1024 + p0 + cp);
      *(float4*)&Bs[r][cp] = x4;
    }
    __syncthreads();
#pragma unroll
    for (int k = 0; k < 16; ++k) {
      float4 a4 = *(const float4*)&As[k][ty * 4];
      float4 b4 = *(const float4*)&Bs[k][tx * 4];
      float av[4] = {a4.x, a4.y, a4.z, a4.w};
      float bv[4] = {b4.x, b4.y, b4.z, b4.w};
#pragma unroll
      for (int i2 = 0; i2 < 4; ++i2)
#pragma unroll
        for (int j2 = 0; j2 < 4; ++j2)
          acc[i2][j2] += av[i2] * bv[j2];
    }
    __syncthreads();
  }
  const float scale = 0.17677669529663687f;  // 32^-0.5
#pragma unroll
  for (int i2 = 0; i2 < 4; ++i2) {
    int o = o0 + ty * 4 + i2;
    float bv = bias[o];
    int sect = o >> 8;                       // 0=q 1=k 2=v (block-uniform)
    int nh = (o >> 5) & 7, d = o & 31;
    size_t hb = ((size_t)(b * 8 + nh)) * 1024;   // bnh * 1024
    if (sect == 0) {
#pragma unroll
      for (int j2 = 0; j2 < 4; ++j2) {
        int p = p0 + tx * 4 + j2;
        qsb[(hb + p) * 32 + d] = f2bs((acc[i2][j2] + bv) * scale);
      }
    } else if (sect == 1) {
#pragma unroll
      for (int j2 = 0; j2 < 4; ++j2) {
        int p = p0 + tx * 4 + j2;
        ksb[(hb + p) * 32 + d] = f2bs(acc[i2][j2] + bv);
      }
    } else {
#pragma unroll
      for (int j2 = 0; j2 < 4; ++j2) {
        int p = p0 + tx * 4 + j2;
        vtb[hb * 32 + (size_t)d * 1024 + p] = f2bs(acc[i2][j2] + bv);
      }
    }
  }
}

// ---------------------------------------------------------------------------
// Kernel 2 (v6): transposed MFMA flash attention.  grid (16, 64), block 256
// = 4 waves; 1 wave = 16 queries x 1024 keys.
//   S^T[key][q] = K.Q^T : A = K-frag (m=key), B = Q^T-frag (n=q)
//   O^T[d][q]   = V^T.P^T: A = V^T-frag (m=d), B = P^T-frag (n=q)
// C/D: col=lane&15 -> q (lane-fixed), row=grp*4+reg -> key/d.
// G tables stored [q][m] (pitch 68); P^T stored [q][key] (pitch 40).
// ---------------------------------------------------------------------------
__global__ __launch_bounds__(256, 4) void attn_mfma(
    const short* __restrict__ qsb, const short* __restrict__ ksb,
    const short* __restrict__ vtb,
    const float* __restrict__ relw_g, const float* __restrict__ relh_g,
    float* __restrict__ am) {
  const int tid = threadIdx.x;
  const int w = tid >> 6, lane = tid & 63;
  const int col = lane & 15, grp = lane >> 4, g8 = grp * 8;
  const int qt = blockIdx.x * 4 + w;       // q-tile 0..63
  const int bnh = blockIdx.y;
  const int q0 = qt * 16;
  const int i = qt >> 1;                   // query row, constant per wave
  const int j0 = (qt & 1) * 16;            // query col base

  const short* Qb = qsb + (size_t)bnh * 32768;
  const short* Kb = ksb + (size_t)bnh * 32768;
  const short* Vb = vtb + (size_t)bnh * 32768;

  __shared__ short Gh_s[4][16][68];  // [wave][q][m]  8.5KB
  __shared__ short Gw_s[4][16][68];  // [wave][q][m]  8.5KB
  __shared__ short Pt_s[4][16][40];  // [wave][q][key] 5KB

  // Q as B-operand fragment (Q^T[k=d][n=q]); 16B contiguous
  short8 b_q = *(const short8*)(Qb + (q0 + col) * 32 + g8);

  // Build G tables transposed: D[m=16t+grp*4+r][q=col] -> G[q][m] b64 writes
  {
    const float* rels[2] = {relh_g, relw_g};
#pragma unroll
    for (int tb = 0; tb < 2; ++tb) {
      const float* relg = rels[tb];
#pragma unroll
      for (int t = 0; t < 4; ++t) {
        int m = 16 * t + col;
        int mc = m > 62 ? 62 : m;            // m=63 junk, never read
        const float* rp = relg + mc * 32 + g8;
        float4 f0 = *(const float4*)rp;
        float4 f1 = *(const float4*)(rp + 4);
        short8 ar;
        ar[0] = f2bs(f0.x); ar[1] = f2bs(f0.y);
        ar[2] = f2bs(f0.z); ar[3] = f2bs(f0.w);
        ar[4] = f2bs(f1.x); ar[5] = f2bs(f1.y);
        ar[6] = f2bs(f1.z); ar[7] = f2bs(f1.w);
        f32x4 d = __builtin_amdgcn_mfma_f32_16x16x32_bf16(
            ar, b_q, (f32x4){0.f, 0.f, 0.f, 0.f}, 0, 0, 0);
        short4v o;
        o[0] = f2bs(d[0]); o[1] = f2bs(d[1]);
        o[2] = f2bs(d[2]); o[3] = f2bs(d[3]);
        short* Gd = tb ? &Gw_s[w][0][0] : &Gh_s[w][0][0];
        *(short4v*)(Gd + col * 68 + 16 * t + grp * 4) = o;
      }
    }
  }
  __asm__ volatile("s_waitcnt lgkmcnt(0)" ::: "memory");

  // Per-lane Gw values are chunk-independent: y = t*16+grp*4+r, preload 8.
  float gw[8];
#pragma unroll
  for (int t = 0; t < 2; ++t)
#pragma unroll
    for (int r = 0; r < 4; ++r)
      gw[t * 4 + r] =
          bs2f(Gw_s[w][col][t * 16 + grp * 4 + r - j0 - col + 31]);

  const short8 a_one = {0x3F80, 0x3F80, 0x3F80, 0x3F80,
                        0x3F80, 0x3F80, 0x3F80, 0x3F80};

  f32x4 acc0 = {0.f, 0.f, 0.f, 0.f};   // O^T d = grp*4+r,     q = col
  f32x4 acc1 = {0.f, 0.f, 0.f, 0.f};   // O^T d = 16+grp*4+r
  f32x4 accl = {0.f, 0.f, 0.f, 0.f};   // l[q=col] in every reg

  short8 k0 = *(const short8*)(Kb + (size_t)(col) * 32 + g8);
  short8 k1 = *(const short8*)(Kb + (size_t)(16 + col) * 32 + g8);
  short8 v0 = *(const short8*)(Vb + (size_t)col * 1024 + g8);
  short8 v1 = *(const short8*)(Vb + (size_t)(16 + col) * 1024 + g8);

#pragma unroll 1
  for (int c = 0; c < 32; ++c) {
    short8 ck0 = k0, ck1 = k1, cv0 = v0, cv1 = v1;
    if (c + 1 < 32) {
      int kb = (c + 1) * 32;
      k0 = *(const short8*)(Kb + (size_t)(kb + col) * 32 + g8);
      k1 = *(const short8*)(Kb + (size_t)(kb + 16 + col) * 32 + g8);
      v0 = *(const short8*)(Vb + (size_t)col * 1024 + kb + g8);
      v1 = *(const short8*)(Vb + (size_t)(16 + col) * 1024 + kb + g8);
    }
    // S^T[key][q]: keys c*32 + (t*16+grp*4+r), q = q0+col
    f32x4 s0 = __builtin_amdgcn_mfma_f32_16x16x32_bf16(
        ck0, b_q, (f32x4){0.f, 0.f, 0.f, 0.f}, 0, 0, 0);
    f32x4 s1 = __builtin_amdgcn_mfma_f32_16x16x32_bf16(
        ck1, b_q, (f32x4){0.f, 0.f, 0.f, 0.f}, 0, 0, 0);
    float gh = bs2f(Gh_s[w][col][c - i + 31]);   // broadcast read
    short4v p0, p1;
#pragma unroll
    for (int r = 0; r < 4; ++r) p0[r] = f2bs(__expf(s0[r] + gh + gw[r]));
#pragma unroll
    for (int r = 0; r < 4; ++r) p1[r] = f2bs(__expf(s1[r] + gh + gw[4 + r]));
    *(short4v*)&Pt_s[w][col][grp * 4] = p0;        // keys 0..15 of chunk
    *(short4v*)&Pt_s[w][col][16 + grp * 4] = p1;   // keys 16..31
    __asm__ volatile("s_waitcnt lgkmcnt(0)" ::: "memory");
    short8 a_p = *(const short8*)&Pt_s[w][col][g8];  // P^T B-frag, b128
    acc0 = __builtin_amdgcn_mfma_f32_16x16x32_bf16(cv0, a_p, acc0, 0, 0, 0);
    acc1 = __builtin_amdgcn_mfma_f32_16x16x32_bf16(cv1, a_p, acc1, 0, 0, 0);
    accl = __builtin_amdgcn_mfma_f32_16x16x32_bf16(a_one, a_p, accl, 0, 0, 0);
  }

  // epilogue: all-ones A => every accl reg holds l[q=col]
  float rn = 1.0f / accl[0];
  float* amb = am + (size_t)bnh * 32768;
#pragma unroll
  for (int r = 0; r < 4; ++r) {
    amb[(size_t)(grp * 4 + r) * 1024 + q0 + col] = acc0[r] * rn;
    amb[(size_t)(16 + grp * 4 + r) * 1024 + q0 + col] = acc1[r] * rn;
  }
}

// ---------------------------------------------------------------------------
// Kernel 3: output projection GEMM, fp32 out channels [256,512).
// grid (16, 4, 8), block 256.
// ---------------------------------------------------------------------------
__global__ __launch_bounds__(256) void proj_gemm(
    const float* __restrict__ W, const float* __restrict__ Am,
    const float* __restrict__ bias, float* __restrict__ out) {
  const int b = blockIdx.z;
  const int p0 = blockIdx.x * 64;
  const int o0 = blockIdx.y * 64;
  const int tid = threadIdx.x;
  const int tx = tid & 15, ty = tid >> 4;
  __shared__ float As[16][64];
  __shared__ float Bs[16][64];
  float acc[4][4] = {};
  const float* Ab = Am + (size_t)b * 256 * 1024;
  for (int c0 = 0; c0 < 256; c0 += 16) {
    {
      int r = tid >> 2, c4 = (tid & 3) * 4;
      float4 w4 = *(const float4*)(W + (size_t)(o0 + r) * 256 + c0 + c4);
      As[c4 + 0][r] = w4.x; As[c4 + 1][r] = w4.y;
      As[c4 + 2][r] = w4.z; As[c4 + 3][r] = w4.w;
    }
    {
      int r = tid >> 4, cp = (tid & 15) * 4;
      float4 x4 = *(const float4*)(Ab + (size_t)(c0 + r) * 1024 + p0 + cp);
      *(float4*)&Bs[r][cp] = x4;
    }
    __syncthreads();
#pragma unroll
    for (int k = 0; k < 16; ++k) {
      float4 a4 = *(const float4*)&As[k][ty * 4];
      float4 b4 = *(const float4*)&Bs[k][tx * 4];
      float av[4] = {a4.x, a4.y, a4.z, a4.w};
      float bv[4] = {b4.x, b4.y, b4.z, b4.w};
#pragma unroll
      for (int i2 = 0; i2 < 4; ++i2)
#pragma unroll
        for (int j2 = 0; j2 < 4; ++j2)
          acc[i2][j2] += av[i2] * bv[j2];
    }
    __syncthreads();
  }
#pragma unroll
  for (int i2 = 0; i2 < 4; ++i2) {
    int o = o0 + ty * 4 + i2;
    float bv = bias[o];
    float4 r4 = make_float4(acc[i2][0] + bv, acc[i2][1] + bv,
                            acc[i2][2] + bv, acc[i2][3] + bv);
    *(float4*)&out[((size_t)b * 512 + 256 + o) * 1024 + p0 + tx * 4] = r4;
  }
}

// ---------------------------------------------------------------------------
// Kernel 4 (v5): LDS-staged MFMA implicit-GEMM 3x3 conv (round 11,
// unchanged).  grid (32, 2, 8), block 256.
// ---------------------------------------------------------------------------
__global__ __launch_bounds__(256) void conv_mfma(
    const short* __restrict__ xt, const short* __restrict__ Wb,
    const float* __restrict__ bias, float* __restrict__ out) {
  const int tid = threadIdx.x;
  const int w = tid >> 6, lane = tid & 63;
  const int col = lane & 15, grp = lane >> 4, g8 = grp * 8;
  const int r0 = blockIdx.x;            // output row 0..31
  const int oh = blockIdx.y;            // o half 0/1
  const int bb = blockIdx.z;

  __shared__ short xs[3][34][264];      // pitch 264: even bank spread

  {
    const short* src = xt + (((size_t)bb * 34 + r0) * 34) * 256;
    for (int g = tid; g < 3264; g += 256) {       // 3*34*32 8-short groups
      int row = g / 1088;                          // 34*32
      int rem = g - row * 1088;
      int cc = rem >> 5, chg = rem & 31;
      short8 v = *(const short8*)(src + (row * 34 + cc) * 256 + chg * 8);
      *(short8*)&xs[row][cc][chg * 8] = v;
    }
  }
  __syncthreads();

  const int ob0 = oh * 128 + w * 16;    // first o-tile
  const int ob1 = ob0 + 64;             // second o-tile
  const short* Wa0 = Wb + (ob0 + col) * 256 + g8;
  const short* Wa1 = Wb + (ob1 + col) * 256 + g8;

  f32x4 acc00 = {0.f, 0.f, 0.f, 0.f};
  f32x4 acc01 = {0.f, 0.f, 0.f, 0.f};
  f32x4 acc10 = {0.f, 0.f, 0.f, 0.f};
  f32x4 acc11 = {0.f, 0.f, 0.f, 0.f};

#pragma unroll 1
  for (int tap = 0; tap < 9; ++tap) {
    const int u = (tap * 11) >> 5, v = tap - 3 * u;   // exact for tap<9
    const short* wa0 = Wa0 + tap * 65536;
    const short* wa1 = Wa1 + tap * 65536;
    const short* xb0 = &xs[u][col + v][g8];
    const short* xb1 = &xs[u][col + 16 + v][g8];
#pragma unroll
    for (int c8 = 0; c8 < 8; ++c8) {
      const int chb = c8 * 32;
      short8 a0 = *(const short8*)(wa0 + chb);
      short8 a1 = *(const short8*)(wa1 + chb);
      short8 b0 = *(const short8*)(xb0 + chb);
      short8 b1 = *(const short8*)(xb1 + chb);
      acc00 = __builtin_amdgcn_mfma_f32_16x16x32_bf16(a0, b0, acc00, 0, 0, 0);
      acc01 = __builtin_amdgcn_mfma_f32_16x16x32_bf16(a0, b1, acc01, 0, 0, 0);
      acc10 = __builtin_amdgcn_mfma_f32_16x16x32_bf16(a1, b0, acc10, 0, 0, 0);
      acc11 = __builtin_amdgcn_mfma_f32_16x16x32_bf16(a1, b1, acc11, 0, 0, 0);
    }
  }

  float* ob = out + (size_t)bb * 512 * 1024 + r0 * 32;
#pragma unroll
  for (int r = 0; r < 4; ++r) {
    int o0 = ob0 + grp * 4 + r;
    int o1 = ob1 + grp * 4 + r;
    float bv0 = bias[o0], bv1 = bias[o1];
    ob[(size_t)o0 * 1024 + col]      = acc00[r] + bv0;
    ob[(size_t)o0 * 1024 + 16 + col] = acc01[r] + bv0;
    ob[(size_t)o1 * 1024 + col]      = acc10[r] + bv1;
    ob[(size_t)o1 * 1024 + 16 + col] = acc11[r] + bv1;
  }
}

// ---------------------------------------------------------------------------
extern "C" void kernel_launch(void* const* d_in, const int* in_sizes, int n_in,
                              void* d_out, int out_size, void* d_ws, size_t ws_size,
                              hipStream_t stream) {
  const float* x      = (const float*)d_in[0];
  const float* w_qkv  = (const float*)d_in[1];
  const float* b_qkv  = (const float*)d_in[2];
  const float* w_attn = (const float*)d_in[3];
  const float* b_attn = (const float*)d_in[4];
  const float* w_out  = (const float*)d_in[5];
  const float* b_out  = (const float*)d_in[6];
  const float* relw   = (const float*)d_in[7];
  const float* relh   = (const float*)d_in[8];
  float* out = (float*)d_out;

  // ws: qsb bf16 4MB | ksb 4MB | vtb 4MB | am f32 8MB | xt bf16 ~4.74MB
  //     (at 20MB) | Wb bf16 ~1.18MB (at 25MB).  Total ~26.2MB.
  short* qsb = (short*)d_ws;
  short* ksb = qsb + (size_t)2 * 1024 * 1024;
  short* vtb = ksb + (size_t)2 * 1024 * 1024;
  float* am  = (float*)((char*)d_ws + (size_t)12 * 1024 * 1024);
  short* xt  = (short*)((char*)d_ws + (size_t)20 * 1024 * 1024);
  short* Wb  = (short*)((char*)d_ws + (size_t)25 * 1024 * 1024);

  xpose<<<dim3(8, 34), 256, 0, stream>>>(x, xt);
  wpack<<<2304, 256, 0, stream>>>(w_out, Wb);
  qkv_gemm<<<dim3(16, 12, 8), 256, 0, stream>>>(w_qkv, x, b_qkv, qsb, ksb, vtb);
  attn_mfma<<<dim3(16, 64), 256, 0, stream>>>(qsb, ksb, vtb, relw, relh, am);
  proj_gemm<<<dim3(16, 4, 8), 256, 0, stream>>>(w_attn, am, b_attn, out);
  conv_mfma<<<dim3(32, 2, 8), 256, 0, stream>>>(xt, Wb, b_out, out);
}

// Round 13
// 227.334 us; speedup vs baseline: 1.0831x; 1.0831x over previous
//
#include <hip/hip_runtime.h>
#include <hip/hip_bf16.h>

// Round-2 finding: ALL inputs and the output are FP32.
// Round-12 post-mortem: attn at 57us regardless of conflict fixes -> the
// binding constraint is global-load serialization: at VGPR_Count=40 the
// compiler drops register prefetch and sinks K/V loads to use (3rd time:
// r8/r10 conv, r11/r12 attn).  Round 13: K/V fragments are identical for
// all 4 waves of a block (same bnh) -> stage cooperatively in double-
// buffered LDS (wave w stages fragment w, 4 VGPRs only, written just
// before the end-of-chunk barrier); all waves read all fragments as
// lane-linear conflict-free ds_read_b128.  Global gather work /4.

typedef __hip_bfloat16 bf16;
using short8 = __attribute__((ext_vector_type(8))) short;
using short4v = __attribute__((ext_vector_type(4))) short;
using f32x4 = __attribute__((ext_vector_type(4))) float;

__device__ __forceinline__ short f2bs(float f) {
  union { bf16 b; short s; } u; u.b = __float2bfloat16(f); return u.s;
}
__device__ __forceinline__ float bs2f(short s) {
  union { unsigned u; float f; } x; x.u = ((unsigned)(unsigned short)s) << 16;
  return x.f;
}

// ---------------------------------------------------------------------------
// Prepass A: xt[b][34][34][256] bf16 = x NCHW -> spatial-major channel-contig
// with zero halo ring.  grid (8, 34), block 256.
// ---------------------------------------------------------------------------
__global__ __launch_bounds__(256) void xpose(
    const float* __restrict__ X, short* __restrict__ xt) {
  const int b = blockIdx.x, r = blockIdx.y;   // r in 0..33 (halo coords)
  const int tid = threadIdx.x;
  const bool rin = (r >= 1) && (r <= 32);
  for (int idx = tid; idx < 34 * 256; idx += 256) {
    int cc = idx >> 8, c = idx & 255;
    float v = 0.f;
    if (rin && cc >= 1 && cc <= 32)
      v = X[((size_t)b * 256 + c) * 1024 + (r - 1) * 32 + (cc - 1)];
    xt[(((size_t)b * 34 + r) * 34 + cc) * 256 + c] = f2bs(v);
  }
}

// ---------------------------------------------------------------------------
// Prepass B: Wb[tap][o][c] bf16 from w_out[o][c][3][3].  grid 2304, block 256.
// ---------------------------------------------------------------------------
__global__ __launch_bounds__(256) void wpack(
    const float* __restrict__ Wc, short* __restrict__ Wb) {
  int idx = blockIdx.x * 256 + threadIdx.x;   // tap*65536 + o*256 + c
  int tap = idx >> 16;
  int rest = idx & 65535;
  int o = rest >> 8, c = rest & 255;
  Wb[idx] = f2bs(Wc[((size_t)o * 256 + c) * 9 + tap]);
}

// ---------------------------------------------------------------------------
// Kernel 1: QKV 1x1 conv as GEMM.  Epilogue emits MFMA-ready bf16:
//   qsb[bnh][q][d] (scaled) | ksb[bnh][key][d] | vtb[bnh][d][key]
// grid (16, 12, 8), block 256.
// ---------------------------------------------------------------------------
__global__ __launch_bounds__(256) void qkv_gemm(
    const float* __restrict__ W, const float* __restrict__ X,
    const float* __restrict__ bias,
    short* __restrict__ qsb, short* __restrict__ ksb, short* __restrict__ vtb) {
  const int b  = blockIdx.z;
  const int p0 = blockIdx.x * 64;
  const int o0 = blockIdx.y * 64;
  const int tid = threadIdx.x;
  const int tx = tid & 15, ty = tid >> 4;
  __shared__ float As[16][64];   // [k][o]
  __shared__ float Bs[16][64];   // [k][p]
  float acc[4][4] = {};
  const float* Xb = X + (size_t)b * 256 * 1024;
  for (int c0 = 0; c0 < 256; c0 += 16) {
    {
      int r = tid >> 2, c4 = (tid & 3) * 4;
      float4 w4 = *(const float4*)(W + (size_t)(o0 + r) * 256 + c0 + c4);
      As[c4 + 0][r] = w4.x; As[c4 + 1][r] = w4.y;
      As[c4 + 2][r] = w4.z; As[c4 + 3][r] = w4.w;
    }
    {
      int r = tid >> 4, cp = (tid & 15) * 4;
      float4 x4 = *(const float4*)(Xb + (size_t)(c0 + r) * 1024 + p0 + cp);
      *(float4*)&Bs[r][cp] = x4;
    }
    __syncthreads();
#pragma unroll
    for (int k = 0; k < 16; ++k) {
      float4 a4 = *(const float4*)&As[k][ty * 4];
      float4 b4 = *(const float4*)&Bs[k][tx * 4];
      float av[4] = {a4.x, a4.y, a4.z, a4.w};
      float bv[4] = {b4.x, b4.y, b4.z, b4.w};
#pragma unroll
      for (int i2 = 0; i2 < 4; ++i2)
#pragma unroll
        for (int j2 = 0; j2 < 4; ++j2)
          acc[i2][j2] += av[i2] * bv[j2];
    }
    __syncthreads();
  }
  const float scale = 0.17677669529663687f;  // 32^-0.5
#pragma unroll
  for (int i2 = 0; i2 < 4; ++i2) {
    int o = o0 + ty * 4 + i2;
    float bv = bias[o];
    int sect = o >> 8;                       // 0=q 1=k 2=v (block-uniform)
    int nh = (o >> 5) & 7, d = o & 31;
    size_t hb = ((size_t)(b * 8 + nh)) * 1024;   // bnh * 1024
    if (sect == 0) {
#pragma unroll
      for (int j2 = 0; j2 < 4; ++j2) {
        int p = p0 + tx * 4 + j2;
        qsb[(hb + p) * 32 + d] = f2bs((acc[i2][j2] + bv) * scale);
      }
    } else if (sect == 1) {
#pragma unroll
      for (int j2 = 0; j2 < 4; ++j2) {
        int p = p0 + tx * 4 + j2;
        ksb[(hb + p) * 32 + d] = f2bs(acc[i2][j2] + bv);
      }
    } else {
#pragma unroll
      for (int j2 = 0; j2 < 4; ++j2) {
        int p = p0 + tx * 4 + j2;
        vtb[hb * 32 + (size_t)d * 1024 + p] = f2bs(acc[i2][j2] + bv);
      }
    }
  }
}

// ---------------------------------------------------------------------------
// Kernel 2 (v7): transposed MFMA flash attention + cooperative LDS K/V
// staging.  grid (16, 64), block 256 = 4 waves; 1 wave = 16 q x 1024 keys.
// Per 32-key chunk: wave w stages fragment w (k0/k1/v0/v1, 16B/lane) into
// kvb[slot^1]; all waves read all 4 fragments from kvb[slot] (lane-linear
// b128, conflict-free); one __syncthreads per chunk flips slots.
// ---------------------------------------------------------------------------
__global__ __launch_bounds__(256, 4) void attn_mfma(
    const short* __restrict__ qsb, const short* __restrict__ ksb,
    const short* __restrict__ vtb,
    const float* __restrict__ relw_g, const float* __restrict__ relh_g,
    float* __restrict__ am) {
  const int tid = threadIdx.x;
  const int w = tid >> 6, lane = tid & 63;
  const int col = lane & 15, grp = lane >> 4, g8 = grp * 8;
  const int qt = blockIdx.x * 4 + w;       // q-tile 0..63
  const int bnh = blockIdx.y;
  const int q0 = qt * 16;
  const int i = qt >> 1;                   // query row, constant per wave
  const int j0 = (qt & 1) * 16;            // query col base

  const short* Qb = qsb + (size_t)bnh * 32768;
  const short* Kb = ksb + (size_t)bnh * 32768;
  const short* Vb = vtb + (size_t)bnh * 32768;

  __shared__ short Gh_s[4][16][68];  // [wave][q][m]  8.5KB
  __shared__ short Gw_s[4][16][68];  // [wave][q][m]  8.5KB
  __shared__ short Pt_s[4][16][40];  // [wave][q][key] 5KB
  __shared__ short kvb[2][4][512];   // [slot][frag][lane*8]  8KB

  // my wave's staging source: fragment w, per-lane 16B gather
  const short* gsrc;
  int gstep;
  if (w == 0)      { gsrc = Kb + (size_t)col * 32 + g8;          gstep = 1024; }
  else if (w == 1) { gsrc = Kb + (size_t)(16 + col) * 32 + g8;   gstep = 1024; }
  else if (w == 2) { gsrc = Vb + (size_t)col * 1024 + g8;        gstep = 32;   }
  else             { gsrc = Vb + (size_t)(16 + col) * 1024 + g8; gstep = 32;   }

  short8 stg = *(const short8*)gsrc;            // chunk 0 (in flight below)

  // Q as B-operand fragment (Q^T[k=d][n=q]); 16B contiguous
  short8 b_q = *(const short8*)(Qb + (q0 + col) * 32 + g8);

  // Build G tables transposed: D[m=16t+grp*4+r][q=col] -> G[q][m] b64 writes
  {
    const float* rels[2] = {relh_g, relw_g};
#pragma unroll
    for (int tb = 0; tb < 2; ++tb) {
      const float* relg = rels[tb];
#pragma unroll
      for (int t = 0; t < 4; ++t) {
        int m = 16 * t + col;
        int mc = m > 62 ? 62 : m;            // m=63 junk, never read
        const float* rp = relg + mc * 32 + g8;
        float4 f0 = *(const float4*)rp;
        float4 f1 = *(const float4*)(rp + 4);
        short8 ar;
        ar[0] = f2bs(f0.x); ar[1] = f2bs(f0.y);
        ar[2] = f2bs(f0.z); ar[3] = f2bs(f0.w);
        ar[4] = f2bs(f1.x); ar[5] = f2bs(f1.y);
        ar[6] = f2bs(f1.z); ar[7] = f2bs(f1.w);
        f32x4 d = __builtin_amdgcn_mfma_f32_16x16x32_bf16(
            ar, b_q, (f32x4){0.f, 0.f, 0.f, 0.f}, 0, 0, 0);
        short4v o;
        o[0] = f2bs(d[0]); o[1] = f2bs(d[1]);
        o[2] = f2bs(d[2]); o[3] = f2bs(d[3]);
        short* Gd = tb ? &Gw_s[w][0][0] : &Gh_s[w][0][0];
        *(short4v*)(Gd + col * 68 + 16 * t + grp * 4) = o;
      }
    }
  }
  __asm__ volatile("s_waitcnt lgkmcnt(0)" ::: "memory");

  // Per-lane Gw values are chunk-independent: y = t*16+grp*4+r, preload 8.
  float gw[8];
#pragma unroll
  for (int t = 0; t < 2; ++t)
#pragma unroll
    for (int r = 0; r < 4; ++r)
      gw[t * 4 + r] =
          bs2f(Gw_s[w][col][t * 16 + grp * 4 + r - j0 - col + 31]);

  const short8 a_one = {0x3F80, 0x3F80, 0x3F80, 0x3F80,
                        0x3F80, 0x3F80, 0x3F80, 0x3F80};

  f32x4 acc0 = {0.f, 0.f, 0.f, 0.f};   // O^T d = grp*4+r,     q = col
  f32x4 acc1 = {0.f, 0.f, 0.f, 0.f};   // O^T d = 16+grp*4+r
  f32x4 accl = {0.f, 0.f, 0.f, 0.f};   // l[q=col] in every reg

  // commit chunk-0 stage, make visible to all waves
  *(short8*)&kvb[0][w][lane * 8] = stg;
  __syncthreads();

#pragma unroll 1
  for (int c = 0; c < 32; ++c) {
    const int cur = c & 1;
    if (c < 31) stg = *(const short8*)(gsrc + (size_t)(c + 1) * gstep);

    short8 ck0 = *(const short8*)&kvb[cur][0][lane * 8];
    short8 ck1 = *(const short8*)&kvb[cur][1][lane * 8];
    short8 cv0 = *(const short8*)&kvb[cur][2][lane * 8];
    short8 cv1 = *(const short8*)&kvb[cur][3][lane * 8];

    // S^T[key][q]: keys c*32 + (t*16+grp*4+r), q = q0+col
    f32x4 s0 = __builtin_amdgcn_mfma_f32_16x16x32_bf16(
        ck0, b_q, (f32x4){0.f, 0.f, 0.f, 0.f}, 0, 0, 0);
    f32x4 s1 = __builtin_amdgcn_mfma_f32_16x16x32_bf16(
        ck1, b_q, (f32x4){0.f, 0.f, 0.f, 0.f}, 0, 0, 0);
    float gh = bs2f(Gh_s[w][col][c - i + 31]);   // broadcast read
    short4v p0, p1;
#pragma unroll
    for (int r = 0; r < 4; ++r) p0[r] = f2bs(__expf(s0[r] + gh + gw[r]));
#pragma unroll
    for (int r = 0; r < 4; ++r) p1[r] = f2bs(__expf(s1[r] + gh + gw[4 + r]));
    *(short4v*)&Pt_s[w][col][grp * 4] = p0;        // keys 0..15 of chunk
    *(short4v*)&Pt_s[w][col][16 + grp * 4] = p1;   // keys 16..31
    __asm__ volatile("s_waitcnt lgkmcnt(0)" ::: "memory");
    short8 a_p = *(const short8*)&Pt_s[w][col][g8];  // P^T B-frag, b128
    acc0 = __builtin_amdgcn_mfma_f32_16x16x32_bf16(cv0, a_p, acc0, 0, 0, 0);
    acc1 = __builtin_amdgcn_mfma_f32_16x16x32_bf16(cv1, a_p, acc1, 0, 0, 0);
    accl = __builtin_amdgcn_mfma_f32_16x16x32_bf16(a_one, a_p, accl, 0, 0, 0);

    if (c < 31) *(short8*)&kvb[cur ^ 1][w][lane * 8] = stg;  // vmcnt wait here
    __syncthreads();   // everyone done reading cur + next slot fully staged
  }

  // epilogue: all-ones A => every accl reg holds l[q=col]
  float rn = 1.0f / accl[0];
  float* amb = am + (size_t)bnh * 32768;
#pragma unroll
  for (int r = 0; r < 4; ++r) {
    amb[(size_t)(grp * 4 + r) * 1024 + q0 + col] = acc0[r] * rn;
    amb[(size_t)(16 + grp * 4 + r) * 1024 + q0 + col] = acc1[r] * rn;
  }
}

// ---------------------------------------------------------------------------
// Kernel 3: output projection GEMM, fp32 out channels [256,512).
// grid (16, 4, 8), block 256.
// ---------------------------------------------------------------------------
__global__ __launch_bounds__(256) void proj_gemm(
    const float* __restrict__ W, const float* __restrict__ Am,
    const float* __restrict__ bias, float* __restrict__ out) {
  const int b = blockIdx.z;
  const int p0 = blockIdx.x * 64;
  const int o0 = blockIdx.y * 64;
  const int tid = threadIdx.x;
  const int tx = tid & 15, ty = tid >> 4;
  __shared__ float As[16][64];
  __shared__ float Bs[16][64];
  float acc[4][4] = {};
  const float* Ab = Am + (size_t)b * 256 * 1024;
  for (int c0 = 0; c0 < 256; c0 += 16) {
    {
      int r = tid >> 2, c4 = (tid & 3) * 4;
      float4 w4 = *(const float4*)(W + (size_t)(o0 + r) * 256 + c0 + c4);
      As[c4 + 0][r] = w4.x; As[c4 + 1][r] = w4.y;
      As[c4 + 2][r] = w4.z; As[c4 + 3][r] = w4.w;
    }
    {
      int r = tid >> 4, cp = (tid & 15) * 4;
      float4 x4 = *(const float4*)(Ab + (size_t)(c0 + r) * 1024 + p0 + cp);
      *(float4*)&Bs[r][cp] = x4;
    }
    __syncthreads();
#pragma unroll
    for (int k = 0; k < 16; ++k) {
      float4 a4 = *(const float4*)&As[k][ty * 4];
      float4 b4 = *(const float4*)&Bs[k][tx * 4];
      float av[4] = {a4.x, a4.y, a4.z, a4.w};
      float bv[4] = {b4.x, b4.y, b4.z, b4.w};
#pragma unroll
      for (int i2 = 0; i2 < 4; ++i2)
#pragma unroll
        for (int j2 = 0; j2 < 4; ++j2)
          acc[i2][j2] += av[i2] * bv[j2];
    }
    __syncthreads();
  }
#pragma unroll
  for (int i2 = 0; i2 < 4; ++i2) {
    int o = o0 + ty * 4 + i2;
    float bv = bias[o];
    float4 r4 = make_float4(acc[i2][0] + bv, acc[i2][1] + bv,
                            acc[i2][2] + bv, acc[i2][3] + bv);
    *(float4*)&out[((size_t)b * 512 + 256 + o) * 1024 + p0 + tx * 4] = r4;
  }
}

// ---------------------------------------------------------------------------
// Kernel 4 (v5): LDS-staged MFMA implicit-GEMM 3x3 conv (round 11,
// unchanged).  grid (32, 2, 8), block 256.
// ---------------------------------------------------------------------------
__global__ __launch_bounds__(256) void conv_mfma(
    const short* __restrict__ xt, const short* __restrict__ Wb,
    const float* __restrict__ bias, float* __restrict__ out) {
  const int tid = threadIdx.x;
  const int w = tid >> 6, lane = tid & 63;
  const int col = lane & 15, grp = lane >> 4, g8 = grp * 8;
  const int r0 = blockIdx.x;            // output row 0..31
  const int oh = blockIdx.y;            // o half 0/1
  const int bb = blockIdx.z;

  __shared__ short xs[3][34][264];      // pitch 264: even bank spread

  {
    const short* src = xt + (((size_t)bb * 34 + r0) * 34) * 256;
    for (int g = tid; g < 3264; g += 256) {       // 3*34*32 8-short groups
      int row = g / 1088;                          // 34*32
      int rem = g - row * 1088;
      int cc = rem >> 5, chg = rem & 31;
      short8 v = *(const short8*)(src + (row * 34 + cc) * 256 + chg * 8);
      *(short8*)&xs[row][cc][chg * 8] = v;
    }
  }
  __syncthreads();

  const int ob0 = oh * 128 + w * 16;    // first o-tile
  const int ob1 = ob0 + 64;             // second o-tile
  const short* Wa0 = Wb + (ob0 + col) * 256 + g8;
  const short* Wa1 = Wb + (ob1 + col) * 256 + g8;

  f32x4 acc00 = {0.f, 0.f, 0.f, 0.f};
  f32x4 acc01 = {0.f, 0.f, 0.f, 0.f};
  f32x4 acc10 = {0.f, 0.f, 0.f, 0.f};
  f32x4 acc11 = {0.f, 0.f, 0.f, 0.f};

#pragma unroll 1
  for (int tap = 0; tap < 9; ++tap) {
    const int u = (tap * 11) >> 5, v = tap - 3 * u;   // exact for tap<9
    const short* wa0 = Wa0 + tap * 65536;
    const short* wa1 = Wa1 + tap * 65536;
    const short* xb0 = &xs[u][col + v][g8];
    const short* xb1 = &xs[u][col + 16 + v][g8];
#pragma unroll
    for (int c8 = 0; c8 < 8; ++c8) {
      const int chb = c8 * 32;
      short8 a0 = *(const short8*)(wa0 + chb);
      short8 a1 = *(const short8*)(wa1 + chb);
      short8 b0 = *(const short8*)(xb0 + chb);
      short8 b1 = *(const short8*)(xb1 + chb);
      acc00 = __builtin_amdgcn_mfma_f32_16x16x32_bf16(a0, b0, acc00, 0, 0, 0);
      acc01 = __builtin_amdgcn_mfma_f32_16x16x32_bf16(a0, b1, acc01, 0, 0, 0);
      acc10 = __builtin_amdgcn_mfma_f32_16x16x32_bf16(a1, b0, acc10, 0, 0, 0);
      acc11 = __builtin_amdgcn_mfma_f32_16x16x32_bf16(a1, b1, acc11, 0, 0, 0);
    }
  }

  float* ob = out + (size_t)bb * 512 * 1024 + r0 * 32;
#pragma unroll
  for (int r = 0; r < 4; ++r) {
    int o0 = ob0 + grp * 4 + r;
    int o1 = ob1 + grp * 4 + r;
    float bv0 = bias[o0], bv1 = bias[o1];
    ob[(size_t)o0 * 1024 + col]      = acc00[r] + bv0;
    ob[(size_t)o0 * 1024 + 16 + col] = acc01[r] + bv0;
    ob[(size_t)o1 * 1024 + col]      = acc10[r] + bv1;
    ob[(size_t)o1 * 1024 + 16 + col] = acc11[r] + bv1;
  }
}

// ---------------------------------------------------------------------------
extern "C" void kernel_launch(void* const* d_in, const int* in_sizes, int n_in,
                              void* d_out, int out_size, void* d_ws, size_t ws_size,
                              hipStream_t stream) {
  const float* x      = (const float*)d_in[0];
  const float* w_qkv  = (const float*)d_in[1];
  const float* b_qkv  = (const float*)d_in[2];
  const float* w_attn = (const float*)d_in[3];
  const float* b_attn = (const float*)d_in[4];
  const float* w_out  = (const float*)d_in[5];
  const float* b_out  = (const float*)d_in[6];
  const float* relw   = (const float*)d_in[7];
  const float* relh   = (const float*)d_in[8];
  float* out = (float*)d_out;

  // ws: qsb bf16 4MB | ksb 4MB | vtb 4MB | am f32 8MB | xt bf16 ~4.74MB
  //     (at 20MB) | Wb bf16 ~1.18MB (at 25MB).  Total ~26.2MB.
  short* qsb = (short*)d_ws;
  short* ksb = qsb + (size_t)2 * 1024 * 1024;
  short* vtb = ksb + (size_t)2 * 1024 * 1024;
  float* am  = (float*)((char*)d_ws + (size_t)12 * 1024 * 1024);
  short* xt  = (short*)((char*)d_ws + (size_t)20 * 1024 * 1024);
  short* Wb  = (short*)((char*)d_ws + (size_t)25 * 1024 * 1024);

  xpose<<<dim3(8, 34), 256, 0, stream>>>(x, xt);
  wpack<<<2304, 256, 0, stream>>>(w_out, Wb);
  qkv_gemm<<<dim3(16, 12, 8), 256, 0, stream>>>(w_qkv, x, b_qkv, qsb, ksb, vtb);
  attn_mfma<<<dim3(16, 64), 256, 0, stream>>>(qsb, ksb, vtb, relw, relh, am);
  proj_gemm<<<dim3(16, 4, 8), 256, 0, stream>>>(w_attn, am, b_attn, out);
  conv_mfma<<<dim3(32, 2, 8), 256, 0, stream>>>(xt, Wb, b_out, out);
}